// Round 17
// baseline (95.240 us; speedup 1.0000x reference)
//
#include <hip/hip_runtime.h>

#define HDIM    256
#define HHALF   128
#define NTYPE   100
#define RPB     2      // crystals per block
#define SH2     132    // LDS h-row stride in half2 units (128 + 4 pad)
#define THREADS 256

typedef float f32x4_n __attribute__((ext_vector_type(4)));
typedef _Float16 h2_t __attribute__((ext_vector_type(2)));
union H2U { unsigned u; h2_t h; };

__device__ __forceinline__ float silu_f(float x) {
    return x / (1.0f + __expf(-x));
}

#define LD4(p) (*(const float4*)(p))

__device__ __forceinline__ float fdot2u(unsigned a, unsigned b, float c) {
    H2U x, y; x.u = a; y.u = b;
    return __builtin_amdgcn_fdot2(x.h, y.h, c, false);
}

// pack f32 weights into k-paired half2: out[k2*ld + j] = (w[2k2][j], w[2k2+1][j])
// layout: w1h[128][256] | w2h[128][256] | wth[128][100] | wch[128][128] | wlh[128][128]
__global__ __launch_bounds__(256) void convert_kernel(
    const float* __restrict__ w1a, const float* __restrict__ w2a,
    const float* __restrict__ wt,  const float* __restrict__ wc1,
    const float* __restrict__ wl1, unsigned* __restrict__ outw)
{
    const int stride = gridDim.x * blockDim.x;
    for (int i = blockIdx.x * blockDim.x + threadIdx.x; i < 111104; i += stride) {
        const float* src; int k2, j, ld;
        if (i < 32768)      { src = w1a; ld = 256; k2 = i >> 8; j = i & 255; }
        else if (i < 65536) { src = w2a; ld = 256; int t = i - 32768; k2 = t >> 8; j = t & 255; }
        else if (i < 78336) { src = wt;  ld = 100; int t = i - 65536; k2 = t / 100; j = t - 100 * k2; }
        else if (i < 94720) { src = wc1; ld = 128; int t = i - 78336; k2 = t >> 7; j = t & 127; }
        else                { src = wl1; ld = 128; int t = i - 94720; k2 = t >> 7; j = t & 127; }
        H2U u;
        u.h = (h2_t){(_Float16)src[(size_t)(2 * k2) * ld + j],
                     (_Float16)src[(size_t)(2 * k2 + 1) * ld + j]};
        outw[i] = u.u;
    }
}

// 2 rows x 8 cols (lo j0, hi j0+128), 16 k2 (=32 k). dot2: 2 MACs/instr.
__device__ __forceinline__ void gemm_main_h(
    const unsigned* hb, const unsigned* __restrict__ W, float* acc)  // acc[16]
{
    uint4 h0 = *(const uint4*)(hb);
    uint4 h1 = *(const uint4*)(hb + SH2);
#pragma unroll 1
    for (int ko = 0; ko < 4; ++ko) {
        uint4 n0, n1;
        if (ko < 3) {
            n0 = *(const uint4*)(hb + (ko + 1) * 4);
            n1 = *(const uint4*)(hb + SH2 + (ko + 1) * 4);
        }
#pragma unroll
        for (int kk = 0; kk < 4; ++kk) {
            const unsigned* w = W + (size_t)(ko * 4 + kk) * 256;
            uint4 wl = *(const uint4*)w;
            uint4 wh = *(const uint4*)(w + 128);
            const unsigned a0 = (kk == 0) ? h0.x : (kk == 1) ? h0.y : (kk == 2) ? h0.z : h0.w;
            const unsigned a1 = (kk == 0) ? h1.x : (kk == 1) ? h1.y : (kk == 2) ? h1.z : h1.w;
            acc[0] = fdot2u(a0, wl.x, acc[0]); acc[1] = fdot2u(a0, wl.y, acc[1]);
            acc[2] = fdot2u(a0, wl.z, acc[2]); acc[3] = fdot2u(a0, wl.w, acc[3]);
            acc[4] = fdot2u(a0, wh.x, acc[4]); acc[5] = fdot2u(a0, wh.y, acc[5]);
            acc[6] = fdot2u(a0, wh.z, acc[6]); acc[7] = fdot2u(a0, wh.w, acc[7]);
            acc[8]  = fdot2u(a1, wl.x, acc[8]);  acc[9]  = fdot2u(a1, wl.y, acc[9]);
            acc[10] = fdot2u(a1, wl.z, acc[10]); acc[11] = fdot2u(a1, wl.w, acc[11]);
            acc[12] = fdot2u(a1, wh.x, acc[12]); acc[13] = fdot2u(a1, wh.y, acc[13]);
            acc[14] = fdot2u(a1, wh.z, acc[14]); acc[15] = fdot2u(a1, wh.w, acc[15]);
        }
        if (ko < 3) { h0 = n0; h1 = n1; }
    }
}

// 2 rows x 4 cols, NK2 k2-steps, runtime ld2 (half2 units)
template<int NK2>
__device__ __forceinline__ void gemm_2x4h(
    const unsigned* hb, const unsigned* __restrict__ W, const int ld2, float* a)  // a[8]
{
    uint4 h0 = *(const uint4*)(hb);
    uint4 h1 = *(const uint4*)(hb + SH2);
#pragma unroll 1
    for (int ko = 0; ko < NK2 / 4; ++ko) {
        uint4 n0, n1;
        if (ko < NK2 / 4 - 1) {
            n0 = *(const uint4*)(hb + (ko + 1) * 4);
            n1 = *(const uint4*)(hb + SH2 + (ko + 1) * 4);
        }
#pragma unroll
        for (int kk = 0; kk < 4; ++kk) {
            const unsigned* w = W + (size_t)(ko * 4 + kk) * ld2;
            uint4 wv = *(const uint4*)w;
            const unsigned a0 = (kk == 0) ? h0.x : (kk == 1) ? h0.y : (kk == 2) ? h0.z : h0.w;
            const unsigned a1 = (kk == 0) ? h1.x : (kk == 1) ? h1.y : (kk == 2) ? h1.z : h1.w;
            a[0] = fdot2u(a0, wv.x, a[0]); a[1] = fdot2u(a0, wv.y, a[1]);
            a[2] = fdot2u(a0, wv.z, a[2]); a[3] = fdot2u(a0, wv.w, a[3]);
            a[4] = fdot2u(a1, wv.x, a[4]); a[5] = fdot2u(a1, wv.y, a[5]);
            a[6] = fdot2u(a1, wv.z, a[6]); a[7] = fdot2u(a1, wv.w, a[7]);
        }
        if (ko < NK2 / 4 - 1) { h0 = n0; h1 = n1; }
    }
}

template<int NV>
__device__ __forceinline__ void shfl_red(float* a) {
#pragma unroll
    for (int i = 0; i < NV; ++i) a[i] += __shfl_xor(a[i], 32);
}

// R16 structure at RPB=2, 8 blocks/CU. One block = 2 crystals.
__global__ __launch_bounds__(THREADS, 8) void fused_kernel(
    const int* __restrict__ batch, int N,
    const float* __restrict__ t_emb,
    const unsigned* __restrict__ wpk,
    const float* __restrict__ b1a, const float* __restrict__ b2a,
    const float* __restrict__ bc1, const float* __restrict__ bl1,
    const float* __restrict__ wc2, const float* __restrict__ bc2,
    const float* __restrict__ wl2, const float* __restrict__ bl2,
    const float* __restrict__ bt,
    float* __restrict__ out_coord,    // [N,3]
    float* __restrict__ cell_out,     // [B,6]
    f32x4_n* __restrict__ out_logits4)// [N,25] f4
{
    const unsigned* w1h = wpk;            // [128][256]
    const unsigned* w2h = wpk + 32768;    // [128][256]
    const unsigned* wth = wpk + 65536;    // [128][100]
    const unsigned* wch = wpk + 78336;    // [128][128]
    const unsigned* wlh = wpk + 94720;    // [128][128]

    __shared__ unsigned bufA[RPB * SH2];   // h0 / h as half2
    __shared__ unsigned bufB[RPB * SH2];   // h1 / gc,gl as half2
    __shared__ float red[3 * 17 * 32];     // cross-wave partials (slot 17)
    __shared__ float logits_s[RPB * 104];
    __shared__ float coord_s[RPB * 4];
    __shared__ int   lb_s[RPB + 1];
    __shared__ float cnt_s[RPB];

    const int tid = threadIdx.x;
    const int R0  = blockIdx.x * RPB;

    if (tid <= RPB) {
        int v = R0 + tid;
        int lo = 0, hi = N;
        while (lo < hi) { int mid = (lo + hi) >> 1; if (batch[mid] < v) lo = mid + 1; else hi = mid; }
        lb_s[tid] = lo;
    }
    if (tid < 128) {   // stage t_emb rows R0..R0+1 -> half2
        const float4* src = (const float4*)(t_emb + (size_t)R0 * HDIM);
        int r = tid >> 6, kq = tid & 63;
        float4 v = src[r * 64 + kq];
        H2U p0, p1;
        p0.h = (h2_t){(_Float16)v.x, (_Float16)v.y};
        p1.h = (h2_t){(_Float16)v.z, (_Float16)v.w};
        *(uint2*)&bufA[r * SH2 + kq * 2] = make_uint2(p0.u, p1.u);
    }
    __syncthreads();
    if (tid < RPB) cnt_s[tid] = (float)(lb_s[tid + 1] - lb_s[tid]);

    const int cg = tid & 31, j0 = cg * 4;
    const int ksg = tid >> 5;       // 8 K-groups x 16 k2
    const int wv  = tid >> 6;
    const bool lo_h = !(tid & 32);

    float acc[16];

    // ---------------- layer 1: h1 = silu(h0 @ w1a + b1a)   bufA -> bufB
#pragma unroll
    for (int i = 0; i < 16; ++i) acc[i] = 0.f;
    gemm_main_h(&bufA[ksg * 16], w1h + (size_t)(ksg * 16) * 256 + j0, acc);
    shfl_red<16>(acc);
    if (wv && lo_h) {
        float* rp = &red[(wv - 1) * 544 + cg * 17];
#pragma unroll
        for (int i = 0; i < 16; ++i) rp[i] = acc[i];
    }
    __syncthreads();
    if (tid < 32) {
#pragma unroll
        for (int p = 0; p < 3; ++p) {
            const float* rp = &red[p * 544 + tid * 17];
#pragma unroll
            for (int i = 0; i < 16; ++i) acc[i] += rp[i];
        }
        float4 bl = LD4(b1a + j0), bh = LD4(b1a + j0 + 128);
        const float bb_[8] = {bl.x, bl.y, bl.z, bl.w, bh.x, bh.y, bh.z, bh.w};
#pragma unroll
        for (int r = 0; r < 2; ++r) {
            float v[8];
#pragma unroll
            for (int c = 0; c < 8; ++c) v[c] = silu_f(acc[r * 8 + c] + bb_[c]);
            H2U p0, p1, p2, p3;
            p0.h = (h2_t){(_Float16)v[0], (_Float16)v[1]};
            p1.h = (h2_t){(_Float16)v[2], (_Float16)v[3]};
            p2.h = (h2_t){(_Float16)v[4], (_Float16)v[5]};
            p3.h = (h2_t){(_Float16)v[6], (_Float16)v[7]};
            *(uint2*)&bufB[r * SH2 + cg * 2]      = make_uint2(p0.u, p1.u);
            *(uint2*)&bufB[r * SH2 + 64 + cg * 2] = make_uint2(p2.u, p3.u);
        }
    }
    __syncthreads();

    // ---------------- layer 2: h = h1 @ w2a + b2a          bufB -> bufA
#pragma unroll
    for (int i = 0; i < 16; ++i) acc[i] = 0.f;
    gemm_main_h(&bufB[ksg * 16], w2h + (size_t)(ksg * 16) * 256 + j0, acc);
    shfl_red<16>(acc);
    if (wv && lo_h) {
        float* rp = &red[(wv - 1) * 544 + cg * 17];
#pragma unroll
        for (int i = 0; i < 16; ++i) rp[i] = acc[i];
    }
    __syncthreads();
    if (tid < 32) {
#pragma unroll
        for (int p = 0; p < 3; ++p) {
            const float* rp = &red[p * 544 + tid * 17];
#pragma unroll
            for (int i = 0; i < 16; ++i) acc[i] += rp[i];
        }
        float4 bl = LD4(b2a + j0), bh = LD4(b2a + j0 + 128);
        const float bb_[8] = {bl.x, bl.y, bl.z, bl.w, bh.x, bh.y, bh.z, bh.w};
#pragma unroll
        for (int r = 0; r < 2; ++r) {
            float v[8];
#pragma unroll
            for (int c = 0; c < 8; ++c) v[c] = acc[r * 8 + c] + bb_[c];
            H2U p0, p1, p2, p3;
            p0.h = (h2_t){(_Float16)v[0], (_Float16)v[1]};
            p1.h = (h2_t){(_Float16)v[2], (_Float16)v[3]};
            p2.h = (h2_t){(_Float16)v[4], (_Float16)v[5]};
            p3.h = (h2_t){(_Float16)v[6], (_Float16)v[7]};
            *(uint2*)&bufA[r * SH2 + cg * 2]      = make_uint2(p0.u, p1.u);
            *(uint2*)&bufA[r * SH2 + 64 + cg * 2] = make_uint2(p2.u, p3.u);
        }
    }
    __syncthreads();

    // ---------------- logits: h @ wt + bt -> logits_s (f32)
    {
        float la[8];
#pragma unroll
        for (int i = 0; i < 8; ++i) la[i] = 0.f;
        if (cg < 25)
            gemm_2x4h<16>(&bufA[ksg * 16], wth + (size_t)(ksg * 16) * 100 + j0, 100, la);
        shfl_red<8>(la);
        if (wv && lo_h && cg < 25) {
            float* rp = &red[(wv - 1) * 288 + cg * 9];
#pragma unroll
            for (int i = 0; i < 8; ++i) rp[i] = la[i];
        }
        __syncthreads();
        if (tid < 25) {
#pragma unroll
            for (int p = 0; p < 3; ++p) {
                const float* rp = &red[p * 288 + tid * 9];
#pragma unroll
                for (int i = 0; i < 8; ++i) la[i] += rp[i];
            }
            float4 b4 = LD4(bt + j0);
#pragma unroll
            for (int r = 0; r < 2; ++r)
                *(float4*)&logits_s[r * 104 + j0] =
                    make_float4(la[r*4+0] + b4.x, la[r*4+1] + b4.y,
                                la[r*4+2] + b4.z, la[r*4+3] + b4.w);
        }
        __syncthreads();
    }

    // -------- OVERLAP: waves 0-1 head hidden GEMMs || waves 2-3 stream logits
    if (tid < 128) {
        const bool ic  = (tid >= 64);           // wave0 coord, wave1 cell
        const int  hcg = tid & 31, hj0 = hcg * 4;
        const int  hks = (tid >> 5) & 1;        // K-half (64 k2)
        const unsigned* Wh = (ic ? wlh : wch) + (size_t)(hks * 64) * 128 + hj0;
        const float* bb2 = ic ? bl1 : bc1;
        float ha[8];
#pragma unroll
        for (int i = 0; i < 8; ++i) ha[i] = 0.f;
        gemm_2x4h<64>(&bufA[hks * 64], Wh, 128, ha);
        shfl_red<8>(ha);                        // hks pair within the wave
        if (!(tid & 32)) {
            float4 b4 = LD4(bb2 + hj0);
            const int off2 = ic ? 64 : 0;
#pragma unroll
            for (int r = 0; r < 2; ++r) {
                // segment_sum == count*h; scale commutes through the dot
                const float sc = ic ? cnt_s[r] : 1.f;
                float v0 = silu_f(ha[r*4+0] * sc + b4.x);
                float v1 = silu_f(ha[r*4+1] * sc + b4.y);
                float v2 = silu_f(ha[r*4+2] * sc + b4.z);
                float v3 = silu_f(ha[r*4+3] * sc + b4.w);
                H2U p0, p1;
                p0.h = (h2_t){(_Float16)v0, (_Float16)v1};
                p1.h = (h2_t){(_Float16)v2, (_Float16)v3};
                *(uint2*)&bufB[r * SH2 + off2 + hcg * 2] = make_uint2(p0.u, p1.u);
            }
        }
    } else {
        const int st = tid - 128;               // 128 streaming threads
        const f32x4_n* ls4 = (const f32x4_n*)logits_s;   // row stride 26 f4
#pragma unroll 1
        for (int r = 0; r < RPB; ++r) {
            const int base = lb_s[r];
            const int tot  = (lb_s[r + 1] - base) * 25;
            const f32x4_n* lrow = ls4 + r * 26;
            for (int t = st; t < tot; t += 128) {
                unsigned a = (unsigned)t / 25u;
                unsigned q = (unsigned)t - a * 25u;
                f32x4_n v = lrow[q];
                __builtin_nontemporal_store(v, &out_logits4[(size_t)(base + a) * 25 + q]);
            }
        }
    }
    __syncthreads();

    // ---------------- tiny heads (read gc/gl half2)
    if (tid < 6) {
        int r = tid / 3, c = tid - 3 * r;
        float a = 0.f;
#pragma unroll 8
        for (int k2 = 0; k2 < 64; ++k2) {
            H2U u; u.u = bufB[r * SH2 + k2];
            a += (float)u.h.x * wc2[(2 * k2) * 3 + c]
               + (float)u.h.y * wc2[(2 * k2 + 1) * 3 + c];
        }
        coord_s[r * 4 + c] = a + bc2[c];
    } else if (tid < 18) {
        int t2 = tid - 6;
        int r = t2 / 6, c = t2 - 6 * r;
        float a = 0.f;
#pragma unroll 8
        for (int k2 = 0; k2 < 64; ++k2) {
            H2U u; u.u = bufB[r * SH2 + 64 + k2];
            a += (float)u.h.x * wl2[(2 * k2) * 6 + c]
               + (float)u.h.y * wl2[(2 * k2 + 1) * 6 + c];
        }
        cell_out[(size_t)(R0 + r) * 6 + c] = a + bl2[c];
    }
    __syncthreads();

    // ---------------- per-atom coord stream (6 MB, coalesced)
#pragma unroll 1
    for (int r = 0; r < RPB; ++r) {
        const int base = lb_s[r];
        const int tot3 = (lb_s[r + 1] - base) * 3;
        const float c0 = coord_s[r * 4 + 0];
        const float c1 = coord_s[r * 4 + 1];
        const float c2 = coord_s[r * 4 + 2];
        float* oc = out_coord + (size_t)base * 3;
        for (int t = tid; t < tot3; t += THREADS) {
            unsigned a = (unsigned)t / 3u;
            unsigned c = (unsigned)t - a * 3u;
            float v = (c == 0) ? c0 : (c == 1) ? c1 : c2;
            __builtin_nontemporal_store(v, &oc[t]);
        }
    }
}

extern "C" void kernel_launch(void* const* d_in, const int* in_sizes, int n_in,
                              void* d_out, int out_size, void* d_ws, size_t ws_size,
                              hipStream_t stream)
{
    const int*   batch = (const int*)d_in[1];
    const float* t_emb = (const float*)d_in[3];
    const float* w1a = (const float*)d_in[4];
    const float* b1a = (const float*)d_in[5];
    const float* w2a = (const float*)d_in[6];
    const float* b2a = (const float*)d_in[7];
    const float* wc1 = (const float*)d_in[8];
    const float* bc1 = (const float*)d_in[9];
    const float* wc2 = (const float*)d_in[10];
    const float* bc2 = (const float*)d_in[11];
    const float* wl1 = (const float*)d_in[12];
    const float* bl1 = (const float*)d_in[13];
    const float* wl2 = (const float*)d_in[14];
    const float* bl2 = (const float*)d_in[15];
    const float* wt  = (const float*)d_in[16];
    const float* bt  = (const float*)d_in[17];

    const int N = in_sizes[1];        // 500000
    const int B = in_sizes[2] / 9;    // 4096

    float* out        = (float*)d_out;
    float* out_coord  = out;                                   // [N,3]
    float* cell_out   = out + (size_t)N * 3;                   // [B,6]
    float* out_logits = out + (size_t)N * 3 + (size_t)B * 6;   // [N,100]

    unsigned* wpk = (unsigned*)d_ws;                           // 111104 uints

    convert_kernel<<<448, 256, 0, stream>>>(w1a, w2a, wt, wc1, wl1, wpk);

    fused_kernel<<<B / RPB, THREADS, 0, stream>>>(
        batch, N, t_emb, wpk,
        b1a, b2a, bc1, bl1,
        wc2, bc2, wl2, bl2, bt,
        out_coord, cell_out, (f32x4_n*)out_logits);
}

// Round 18
// 87.815 us; speedup vs baseline: 1.0846x; 1.0846x over previous
//
#include <hip/hip_runtime.h>

#define HDIM   256
#define NTYPE  100
#define RPB    16     // crystals per block (= MFMA M-tile)
#define ST     272    // LDS h-row stride in f16 (544B, 16B-aligned, odd 32B mult)
#define THREADS 512

typedef float f32x4_n __attribute__((ext_vector_type(4)));
typedef _Float16 f16x8 __attribute__((ext_vector_type(8)));
typedef float f32x4 __attribute__((ext_vector_type(4)));

#define LD4(p) (*(const float4*)(p))

__device__ __forceinline__ float silu_f(float x) {
    return x / (1.0f + __expf(-x));
}

#define MFMA(a, b, c) __builtin_amdgcn_mfma_f32_16x16x32_f16((a), (b), (c), 0, 0, 0)

// Pack W^T in f16 ([n][k], k contiguous) + precompute lb bounds.
// wpk layout (halves): wp1 65536 | wp2 65536 | wpt 28672 (112 rows, >=100 zero)
//                    | wpc 32768 | wpl 32768 ; then lb[4097] ints.
#define NW_TOT 225280
__global__ __launch_bounds__(256) void prep_kernel(
    const float* __restrict__ w1a, const float* __restrict__ w2a,
    const float* __restrict__ wt,  const float* __restrict__ wc1,
    const float* __restrict__ wl1,
    const int* __restrict__ batch, int N,
    _Float16* __restrict__ outw, int* __restrict__ lb)
{
    const int stride = gridDim.x * blockDim.x;
    for (int i = blockIdx.x * blockDim.x + threadIdx.x; i < NW_TOT + 4097; i += stride) {
        if (i < NW_TOT) {
            float v;
            if (i < 65536) {
                int n = i >> 8, k = i & 255;            v = w1a[(size_t)k * 256 + n];
            } else if (i < 131072) {
                int t = i - 65536; int n = t >> 8, k = t & 255; v = w2a[(size_t)k * 256 + n];
            } else if (i < 159744) {
                int t = i - 131072; int n = t >> 8, k = t & 255;
                v = (n < NTYPE) ? wt[(size_t)k * NTYPE + n] : 0.f;
            } else if (i < 192512) {
                int t = i - 159744; int n = t >> 8, k = t & 255; v = wc1[(size_t)k * 128 + n];
            } else {
                int t = i - 192512; int n = t >> 8, k = t & 255; v = wl1[(size_t)k * 128 + n];
            }
            outw[i] = (_Float16)v;
        } else {
            int v = i - NW_TOT;                 // crystal id 0..4096
            int lo = 0, hi = N;
            while (lo < hi) { int mid = (lo + hi) >> 1; if (batch[mid] < v) lo = mid + 1; else hi = mid; }
            lb[v] = lo;
        }
    }
}

// One block = 16 crystals, 512 threads (8 waves). MFMA 16x16x32_f16 everywhere.
__global__ __launch_bounds__(THREADS, 2) void fused_kernel(
    const float* __restrict__ t_emb,
    const _Float16* __restrict__ wpk, const int* __restrict__ lb,
    const float* __restrict__ b1a, const float* __restrict__ b2a,
    const float* __restrict__ bc1, const float* __restrict__ bl1,
    const float* __restrict__ wc2, const float* __restrict__ bc2,
    const float* __restrict__ wl2, const float* __restrict__ bl2,
    const float* __restrict__ bt,
    float* __restrict__ out_coord,    // [N,3]
    float* __restrict__ cell_out,     // [B,6]
    f32x4_n* __restrict__ out_logits4)// [N,25] f4
{
    const _Float16* wp1 = wpk;
    const _Float16* wp2 = wpk + 65536;
    const _Float16* wpt = wpk + 131072;
    const _Float16* wpc = wpk + 159744;
    const _Float16* wpl = wpk + 192512;

    __shared__ _Float16 bufA[RPB * ST];   // h0, then h
    __shared__ _Float16 bufB[RPB * ST];   // h1, then gc(cols 0..127) / gl(128..255)
    __shared__ float logits_s[RPB * 104];
    __shared__ float coord_s[RPB * 4];
    __shared__ int   lb_s[RPB + 1];
    __shared__ float cnt_s[RPB];

    const int tid = threadIdx.x;
    const int R0  = blockIdx.x * RPB;

    if (tid <= RPB) lb_s[tid] = lb[R0 + tid];

    // stage t_emb rows R0..R0+15 -> f16 LDS (each thread 8 floats)
    {
        int r = tid >> 5, k0 = (tid & 31) * 8;
        float4 v0 = LD4(&t_emb[(size_t)(R0 + r) * HDIM + k0]);
        float4 v1 = LD4(&t_emb[(size_t)(R0 + r) * HDIM + k0 + 4]);
        f16x8 h = {(_Float16)v0.x, (_Float16)v0.y, (_Float16)v0.z, (_Float16)v0.w,
                   (_Float16)v1.x, (_Float16)v1.y, (_Float16)v1.z, (_Float16)v1.w};
        *(f16x8*)&bufA[r * ST + k0] = h;
    }
    __syncthreads();
    if (tid < RPB) cnt_s[tid] = (float)(lb_s[tid + 1] - lb_s[tid]);

    const int lane = tid & 63;
    const int wv   = tid >> 6;     // wave 0..7
    const int lm   = lane & 15;    // A row / B,C col
    const int lk   = lane >> 4;    // k sub-block (x8) / C row group (x4)

    // ---------------- layer 1: h1 = silu(h0 @ w1a + b1a)   bufA -> bufB
    {
        f32x4 a0 = {0.f,0.f,0.f,0.f}, a1 = {0.f,0.f,0.f,0.f};
        const int n0 = wv * 32 + lm, n1 = n0 + 16;
#pragma unroll 2
        for (int k0 = 0; k0 < 8; ++k0) {
            f16x8 af = *(const f16x8*)&bufA[lm * ST + k0 * 32 + lk * 8];
            f16x8 b0 = *(const f16x8*)&wp1[(size_t)n0 * 256 + k0 * 32 + lk * 8];
            f16x8 b1 = *(const f16x8*)&wp1[(size_t)n1 * 256 + k0 * 32 + lk * 8];
            a0 = MFMA(af, b0, a0);
            a1 = MFMA(af, b1, a1);
        }
        float bb0 = b1a[n0], bb1 = b1a[n1];
#pragma unroll
        for (int g = 0; g < 4; ++g) {
            int m = lk * 4 + g;
            bufB[m * ST + n0] = (_Float16)silu_f(a0[g] + bb0);
            bufB[m * ST + n1] = (_Float16)silu_f(a1[g] + bb1);
        }
    }
    __syncthreads();

    // ---------------- layer 2: h = h1 @ w2a + b2a          bufB -> bufA
    {
        f32x4 a0 = {0.f,0.f,0.f,0.f}, a1 = {0.f,0.f,0.f,0.f};
        const int n0 = wv * 32 + lm, n1 = n0 + 16;
#pragma unroll 2
        for (int k0 = 0; k0 < 8; ++k0) {
            f16x8 af = *(const f16x8*)&bufB[lm * ST + k0 * 32 + lk * 8];
            f16x8 b0 = *(const f16x8*)&wp2[(size_t)n0 * 256 + k0 * 32 + lk * 8];
            f16x8 b1 = *(const f16x8*)&wp2[(size_t)n1 * 256 + k0 * 32 + lk * 8];
            a0 = MFMA(af, b0, a0);
            a1 = MFMA(af, b1, a1);
        }
        float bb0 = b2a[n0], bb1 = b2a[n1];
#pragma unroll
        for (int g = 0; g < 4; ++g) {
            int m = lk * 4 + g;
            bufA[m * ST + n0] = (_Float16)(a0[g] + bb0);
            bufA[m * ST + n1] = (_Float16)(a1[g] + bb1);
        }
    }
    __syncthreads();

    // ------- merged phase: logits (waves 0-6) + coord head + cell head (all waves)
    {
        f32x4 aL = {0.f,0.f,0.f,0.f}, aC = aL, aG = aL;
        const bool hasL = (wv < 7);
        const int n = wv * 16 + lm;        // logits col (0..111) / head col (0..127)
#pragma unroll 2
        for (int k0 = 0; k0 < 8; ++k0) {
            f16x8 af = *(const f16x8*)&bufA[lm * ST + k0 * 32 + lk * 8];
            if (hasL) {
                f16x8 bL = *(const f16x8*)&wpt[(size_t)n * 256 + k0 * 32 + lk * 8];
                aL = MFMA(af, bL, aL);
            }
            f16x8 bC = *(const f16x8*)&wpc[(size_t)n * 256 + k0 * 32 + lk * 8];
            aC = MFMA(af, bC, aC);
            f16x8 bG = *(const f16x8*)&wpl[(size_t)n * 256 + k0 * 32 + lk * 8];
            aG = MFMA(af, bG, aG);
        }
        const bool wrL = hasL && (n < NTYPE);
        float btv = wrL ? bt[n] : 0.f;
        float bcv = bc1[n], blv = bl1[n];
#pragma unroll
        for (int g = 0; g < 4; ++g) {
            int m = lk * 4 + g;
            if (wrL) logits_s[m * 104 + n] = aL[g] + btv;
            bufB[m * ST + n]       = (_Float16)silu_f(aC[g] + bcv);
            bufB[m * ST + 128 + n] = (_Float16)silu_f(aG[g] * cnt_s[m] + blv);
        }
    }
    __syncthreads();

    // ---------------- tiny heads
    if (tid < RPB * 3) {
        int r = tid / 3, c = tid - 3 * r;
        float a = 0.f;
#pragma unroll 8
        for (int k = 0; k < 128; ++k)
            a += (float)bufB[r * ST + k] * wc2[k * 3 + c];
        coord_s[r * 4 + c] = a + bc2[c];
    } else if (tid >= 64 && tid < 64 + RPB * 6) {
        int t2 = tid - 64;
        int r = t2 / 6, c = t2 - 6 * r;
        float a = 0.f;
#pragma unroll 8
        for (int k = 0; k < 128; ++k)
            a += (float)bufB[r * ST + 128 + k] * wl2[k * 6 + c];
        cell_out[(size_t)(R0 + r) * 6 + c] = a + bl2[c];
    }
    __syncthreads();

    // ---------------- per-atom streams (coalesced nontemporal)
    const f32x4_n* ls4 = (const f32x4_n*)logits_s;   // row stride 26 f4
#pragma unroll 1
    for (int r = 0; r < RPB; ++r) {
        const int base = lb_s[r];
        const int tot  = (lb_s[r + 1] - base) * 25;
        const f32x4_n* lrow = ls4 + r * 26;
        for (int t = tid; t < tot; t += THREADS) {
            unsigned a = (unsigned)t / 25u;
            unsigned q = (unsigned)t - a * 25u;
            f32x4_n v = lrow[q];
            __builtin_nontemporal_store(v, &out_logits4[(size_t)(base + a) * 25 + q]);
        }
    }
#pragma unroll 1
    for (int r = 0; r < RPB; ++r) {
        const int base = lb_s[r];
        const int tot3 = (lb_s[r + 1] - base) * 3;
        const float c0 = coord_s[r * 4 + 0];
        const float c1 = coord_s[r * 4 + 1];
        const float c2 = coord_s[r * 4 + 2];
        float* oc = out_coord + (size_t)base * 3;
        for (int t = tid; t < tot3; t += THREADS) {
            unsigned a = (unsigned)t / 3u;
            unsigned c = (unsigned)t - a * 3u;
            float v = (c == 0) ? c0 : (c == 1) ? c1 : c2;
            __builtin_nontemporal_store(v, &oc[t]);
        }
    }
}

extern "C" void kernel_launch(void* const* d_in, const int* in_sizes, int n_in,
                              void* d_out, int out_size, void* d_ws, size_t ws_size,
                              hipStream_t stream)
{
    const int*   batch = (const int*)d_in[1];
    const float* t_emb = (const float*)d_in[3];
    const float* w1a = (const float*)d_in[4];
    const float* b1a = (const float*)d_in[5];
    const float* w2a = (const float*)d_in[6];
    const float* b2a = (const float*)d_in[7];
    const float* wc1 = (const float*)d_in[8];
    const float* bc1 = (const float*)d_in[9];
    const float* wc2 = (const float*)d_in[10];
    const float* bc2 = (const float*)d_in[11];
    const float* wl1 = (const float*)d_in[12];
    const float* bl1 = (const float*)d_in[13];
    const float* wl2 = (const float*)d_in[14];
    const float* bl2 = (const float*)d_in[15];
    const float* wt  = (const float*)d_in[16];
    const float* bt  = (const float*)d_in[17];

    const int N = in_sizes[1];        // 500000
    const int B = in_sizes[2] / 9;    // 4096

    float* out        = (float*)d_out;
    float* out_coord  = out;                                   // [N,3]
    float* cell_out   = out + (size_t)N * 3;                   // [B,6]
    float* out_logits = out + (size_t)N * 3 + (size_t)B * 6;   // [N,100]

    _Float16* wpk = (_Float16*)d_ws;                           // 225280 halves
    int*      lbw = (int*)(wpk + NW_TOT);                      // 4097 ints

    prep_kernel<<<1024, 256, 0, stream>>>(w1a, w2a, wt, wc1, wl1, batch, N, wpk, lbw);

    fused_kernel<<<B / RPB, THREADS, 0, stream>>>(
        t_emb, wpk, lbw,
        b1a, b2a, bc1, bl1,
        wc2, bc2, wl2, bl2, bt,
        out_coord, cell_out, (f32x4_n*)out_logits);
}

// Round 20
// 69.096 us; speedup vs baseline: 1.3784x; 1.2709x over previous
//
#include <hip/hip_runtime.h>

#define HDIM   256
#define NTYPE  100
#define RPB    16     // crystals per block (= MFMA M-tile)
#define ST     272    // LDS h-row stride in f16
#define THREADS 512

typedef float f32x4_n __attribute__((ext_vector_type(4)));
typedef _Float16 f16x8 __attribute__((ext_vector_type(8)));
typedef float f32x4 __attribute__((ext_vector_type(4)));

#define LD4(p) (*(const float4*)(p))

__device__ __forceinline__ float silu_f(float x) {
    return x / (1.0f + __expf(-x));
}

#define MFMA(a, b, c) __builtin_amdgcn_mfma_f32_16x16x32_f16((a), (b), (c), 0, 0, 0)

// Pack W^T in f16 ([n][k], k contiguous).
// layout (halves): wp1 65536 | wp2 65536 | wpt 28672 (112 rows, >=100 zero)
//                | wpc 32768 | wpl 32768
#define NW_TOT 225280
__global__ __launch_bounds__(256) void prep_kernel(
    const float* __restrict__ w1a, const float* __restrict__ w2a,
    const float* __restrict__ wt,  const float* __restrict__ wc1,
    const float* __restrict__ wl1, _Float16* __restrict__ outw)
{
    const int stride = gridDim.x * blockDim.x;
    for (int i = blockIdx.x * blockDim.x + threadIdx.x; i < NW_TOT; i += stride) {
        float v;
        if (i < 65536) {
            int n = i >> 8, k = i & 255;            v = w1a[(size_t)k * 256 + n];
        } else if (i < 131072) {
            int t = i - 65536; int n = t >> 8, k = t & 255; v = w2a[(size_t)k * 256 + n];
        } else if (i < 159744) {
            int t = i - 131072; int n = t >> 8, k = t & 255;
            v = (n < NTYPE) ? wt[(size_t)k * NTYPE + n] : 0.f;
        } else if (i < 192512) {
            int t = i - 159744; int n = t >> 8, k = t & 255; v = wc1[(size_t)k * 128 + n];
        } else {
            int t = i - 192512; int n = t >> 8, k = t & 255; v = wl1[(size_t)k * 128 + n];
        }
        outw[i] = (_Float16)v;
    }
}

// One block = 16 crystals, 512 threads (8 waves). MFMA 16x16x32_f16.
// Writes per-crystal tables to ws (tiny); the 206 MB expansion is scatter's job.
__global__ __launch_bounds__(THREADS, 2) void crystal_kernel(
    const int* __restrict__ batch, int N,
    const float* __restrict__ t_emb,
    const _Float16* __restrict__ wpk,
    const float* __restrict__ b1a, const float* __restrict__ b2a,
    const float* __restrict__ bc1, const float* __restrict__ bl1,
    const float* __restrict__ wc2, const float* __restrict__ bc2,
    const float* __restrict__ wl2, const float* __restrict__ bl2,
    const float* __restrict__ bt,
    float* __restrict__ coord_b,     // ws [B,3]
    f32x4_n* __restrict__ logits_b4, // ws [B,25] f4
    float* __restrict__ cell_out)    // d_out+N*3 [B,6]
{
    const _Float16* wp1 = wpk;
    const _Float16* wp2 = wpk + 65536;
    const _Float16* wpt = wpk + 131072;
    const _Float16* wpc = wpk + 159744;
    const _Float16* wpl = wpk + 192512;

    __shared__ _Float16 bufA[RPB * ST];   // h0, then h
    __shared__ _Float16 bufB[RPB * ST];   // h1, then gc(0..127)/gl(128..255)
    __shared__ float logits_s[RPB * 104];
    __shared__ int   lb_s[RPB + 1];
    __shared__ float cnt_s[RPB];

    const int tid = threadIdx.x;
    const int R0  = blockIdx.x * RPB;

    // per-crystal counts via binary search on sorted batch
    if (tid <= RPB) {
        int v = R0 + tid;
        int lo = 0, hi = N;
        while (lo < hi) { int mid = (lo + hi) >> 1; if (batch[mid] < v) lo = mid + 1; else hi = mid; }
        lb_s[tid] = lo;
    }

    // stage t_emb rows R0..R0+15 -> f16 LDS (each thread 8 floats)
    {
        int r = tid >> 5, k0 = (tid & 31) * 8;
        float4 v0 = LD4(&t_emb[(size_t)(R0 + r) * HDIM + k0]);
        float4 v1 = LD4(&t_emb[(size_t)(R0 + r) * HDIM + k0 + 4]);
        f16x8 h = {(_Float16)v0.x, (_Float16)v0.y, (_Float16)v0.z, (_Float16)v0.w,
                   (_Float16)v1.x, (_Float16)v1.y, (_Float16)v1.z, (_Float16)v1.w};
        *(f16x8*)&bufA[r * ST + k0] = h;
    }
    __syncthreads();
    if (tid < RPB) cnt_s[tid] = (float)(lb_s[tid + 1] - lb_s[tid]);

    const int lane = tid & 63;
    const int wv   = tid >> 6;     // wave 0..7
    const int lm   = lane & 15;    // A row / B col
    const int lk   = lane >> 4;    // k sub-block (x8) / C row group (x4)

    // ---------------- layer 1: h1 = silu(h0 @ w1a + b1a)   bufA -> bufB
    {
        f32x4 a0 = {0.f,0.f,0.f,0.f}, a1 = {0.f,0.f,0.f,0.f};
        const int n0 = wv * 32 + lm, n1 = n0 + 16;
#pragma unroll 2
        for (int k0 = 0; k0 < 8; ++k0) {
            f16x8 af = *(const f16x8*)&bufA[lm * ST + k0 * 32 + lk * 8];
            f16x8 b0 = *(const f16x8*)&wp1[(size_t)n0 * 256 + k0 * 32 + lk * 8];
            f16x8 b1 = *(const f16x8*)&wp1[(size_t)n1 * 256 + k0 * 32 + lk * 8];
            a0 = MFMA(af, b0, a0);
            a1 = MFMA(af, b1, a1);
        }
        float bb0 = b1a[n0], bb1 = b1a[n1];
#pragma unroll
        for (int g = 0; g < 4; ++g) {
            int m = lk * 4 + g;
            bufB[m * ST + n0] = (_Float16)silu_f(a0[g] + bb0);
            bufB[m * ST + n1] = (_Float16)silu_f(a1[g] + bb1);
        }
    }
    __syncthreads();

    // ---------------- layer 2: h = h1 @ w2a + b2a          bufB -> bufA
    {
        f32x4 a0 = {0.f,0.f,0.f,0.f}, a1 = {0.f,0.f,0.f,0.f};
        const int n0 = wv * 32 + lm, n1 = n0 + 16;
#pragma unroll 2
        for (int k0 = 0; k0 < 8; ++k0) {
            f16x8 af = *(const f16x8*)&bufB[lm * ST + k0 * 32 + lk * 8];
            f16x8 b0 = *(const f16x8*)&wp2[(size_t)n0 * 256 + k0 * 32 + lk * 8];
            f16x8 b1 = *(const f16x8*)&wp2[(size_t)n1 * 256 + k0 * 32 + lk * 8];
            a0 = MFMA(af, b0, a0);
            a1 = MFMA(af, b1, a1);
        }
        float bb0 = b2a[n0], bb1 = b2a[n1];
#pragma unroll
        for (int g = 0; g < 4; ++g) {
            int m = lk * 4 + g;
            bufA[m * ST + n0] = (_Float16)(a0[g] + bb0);
            bufA[m * ST + n1] = (_Float16)(a1[g] + bb1);
        }
    }
    __syncthreads();

    // ------- merged: logits (waves 0-6) + coord head + cell head (all waves)
    {
        f32x4 aL = {0.f,0.f,0.f,0.f}, aC = aL, aG = aL;
        const bool hasL = (wv < 7);
        const int n = wv * 16 + lm;
#pragma unroll 2
        for (int k0 = 0; k0 < 8; ++k0) {
            f16x8 af = *(const f16x8*)&bufA[lm * ST + k0 * 32 + lk * 8];
            if (hasL) {
                f16x8 bL = *(const f16x8*)&wpt[(size_t)n * 256 + k0 * 32 + lk * 8];
                aL = MFMA(af, bL, aL);
            }
            f16x8 bC = *(const f16x8*)&wpc[(size_t)n * 256 + k0 * 32 + lk * 8];
            aC = MFMA(af, bC, aC);
            f16x8 bG = *(const f16x8*)&wpl[(size_t)n * 256 + k0 * 32 + lk * 8];
            aG = MFMA(af, bG, aG);
        }
        const bool wrL = hasL && (n < NTYPE);
        float btv = wrL ? bt[n] : 0.f;
        float bcv = bc1[n], blv = bl1[n];
#pragma unroll
        for (int g = 0; g < 4; ++g) {
            int m = lk * 4 + g;
            if (wrL) logits_s[m * 104 + n] = aL[g] + btv;
            bufB[m * ST + n]       = (_Float16)silu_f(aC[g] + bcv);
            bufB[m * ST + 128 + n] = (_Float16)silu_f(aG[g] * cnt_s[m] + blv);
        }
    }
    __syncthreads();

    // ---------------- logits table: ALL 400 f4 writes, strided over 512 thr
    {
        const f32x4_n* ls4 = (const f32x4_n*)logits_s;
        for (int t2 = tid; t2 < 25 * RPB; t2 += THREADS) {
            int r = t2 / 25, q = t2 - 25 * r;
            logits_b4[(size_t)(R0 + r) * 25 + q] = ls4[r * 26 + q];
        }
    }

    // ---------------- tiny heads
    if (tid < RPB * 3) {                 // coord rows -> coord_b
        int r = tid / 3, c = tid - 3 * r;
        float a = 0.f;
#pragma unroll 8
        for (int k = 0; k < 128; ++k)
            a += (float)bufB[r * ST + k] * wc2[k * 3 + c];
        coord_b[(size_t)(R0 + r) * 3 + c] = a + bc2[c];
    } else if (tid >= 64 && tid < 64 + RPB * 6) {   // cell rows -> d_out
        int t2 = tid - 64;
        int r = t2 / 6, c = t2 - 6 * r;
        float a = 0.f;
#pragma unroll 8
        for (int k = 0; k < 128; ++k)
            a += (float)bufB[r * ST + 128 + k] * wl2[k * 6 + c];
        cell_out[(size_t)(R0 + r) * 6 + c] = a + bl2[c];
    }
}

// Gather per-crystal tables to per-atom outputs. 2048 blocks -> full store-queue
// depth; proven ~6 TB/s in the split structure (R4/R7).
__global__ __launch_bounds__(256) void scatter_kernel(
    const int* __restrict__ batch,
    const float*  __restrict__ coord_b,
    const f32x4_n* __restrict__ logits_b4,  // [B][25] f4
    float*  __restrict__ out_coord,         // [N*3]
    f32x4_n* __restrict__ out_logits4,      // [N*25] f4
    int N)
{
    const int stride = gridDim.x * blockDim.x;
    const int g0 = blockIdx.x * blockDim.x + threadIdx.x;

    const int tot_c = N * 3;
    for (int g = g0; g < tot_c; g += stride) {
        unsigned ug = (unsigned)g;
        unsigned i = ug / 3u;
        unsigned c = ug - i * 3u;
        __builtin_nontemporal_store(coord_b[3u * (unsigned)batch[i] + c], &out_coord[g]);
    }

    const int tot_l = N * 25;
    for (int g = g0; g < tot_l; g += stride) {
        unsigned ug = (unsigned)g;
        unsigned i = ug / 25u;
        unsigned q = ug - i * 25u;
        f32x4_n v = logits_b4[25u * (unsigned)batch[i] + q];
        __builtin_nontemporal_store(v, &out_logits4[g]);
    }
}

extern "C" void kernel_launch(void* const* d_in, const int* in_sizes, int n_in,
                              void* d_out, int out_size, void* d_ws, size_t ws_size,
                              hipStream_t stream)
{
    const int*   batch = (const int*)d_in[1];
    const float* t_emb = (const float*)d_in[3];
    const float* w1a = (const float*)d_in[4];
    const float* b1a = (const float*)d_in[5];
    const float* w2a = (const float*)d_in[6];
    const float* b2a = (const float*)d_in[7];
    const float* wc1 = (const float*)d_in[8];
    const float* bc1 = (const float*)d_in[9];
    const float* wc2 = (const float*)d_in[10];
    const float* bc2 = (const float*)d_in[11];
    const float* wl1 = (const float*)d_in[12];
    const float* bl1 = (const float*)d_in[13];
    const float* wl2 = (const float*)d_in[14];
    const float* bl2 = (const float*)d_in[15];
    const float* wt  = (const float*)d_in[16];
    const float* bt  = (const float*)d_in[17];

    const int N = in_sizes[1];        // 500000
    const int B = in_sizes[2] / 9;    // 4096

    float* out        = (float*)d_out;
    float* out_coord  = out;                                   // [N,3]
    float* cell_out   = out + (size_t)N * 3;                   // [B,6]
    float* out_logits = out + (size_t)N * 3 + (size_t)B * 6;   // [N,100]

    _Float16* wpk   = (_Float16*)d_ws;                         // 225280 halves
    float* logits_b = (float*)(wpk + NW_TOT);                  // B*100 floats
    float* coord_b  = logits_b + (size_t)B * NTYPE;            // B*3 floats

    prep_kernel<<<880, 256, 0, stream>>>(w1a, w2a, wt, wc1, wl1, wpk);

    crystal_kernel<<<B / RPB, THREADS, 0, stream>>>(
        batch, N, t_emb, wpk,
        b1a, b2a, bc1, bl1,
        wc2, bc2, wl2, bl2, bt,
        coord_b, (f32x4_n*)logits_b, cell_out);

    scatter_kernel<<<2048, 256, 0, stream>>>(
        batch, coord_b, (const f32x4_n*)logits_b,
        out_coord, (f32x4_n*)out_logits, N);
}

// Round 21
// 68.452 us; speedup vs baseline: 1.3914x; 1.0094x over previous
//
#include <hip/hip_runtime.h>

#define HDIM   256
#define NTYPE  100
#define RPB    16     // crystals per block (= MFMA M-tile)
#define ST     272    // LDS h-row stride in f16
#define THREADS 512

typedef float f32x4_n __attribute__((ext_vector_type(4)));
typedef _Float16 f16x8 __attribute__((ext_vector_type(8)));
typedef float f32x4 __attribute__((ext_vector_type(4)));

#define LD4(p) (*(const float4*)(p))

__device__ __forceinline__ float silu_f(float x) {
    return x / (1.0f + __expf(-x));
}

#define MFMA(a, b, c) __builtin_amdgcn_mfma_f32_16x16x32_f16((a), (b), (c), 0, 0, 0)

// Pack W^T in f16 ([n][k], k contiguous) + precompute lb bounds (parallel here,
// serial-latency poison if done per-block in crystal).
// layout (halves): wp1 65536 | wp2 65536 | wpt 28672 | wpc 32768 | wpl 32768
#define NW_TOT 225280
__global__ __launch_bounds__(256) void prep_kernel(
    const float* __restrict__ w1a, const float* __restrict__ w2a,
    const float* __restrict__ wt,  const float* __restrict__ wc1,
    const float* __restrict__ wl1,
    const int* __restrict__ batch, int N,
    _Float16* __restrict__ outw, int* __restrict__ lb)
{
    const int stride = gridDim.x * blockDim.x;
    for (int i = blockIdx.x * blockDim.x + threadIdx.x; i < NW_TOT + 4097; i += stride) {
        if (i < NW_TOT) {
            float v;
            if (i < 65536) {
                int n = i >> 8, k = i & 255;            v = w1a[(size_t)k * 256 + n];
            } else if (i < 131072) {
                int t = i - 65536; int n = t >> 8, k = t & 255; v = w2a[(size_t)k * 256 + n];
            } else if (i < 159744) {
                int t = i - 131072; int n = t >> 8, k = t & 255;
                v = (n < NTYPE) ? wt[(size_t)k * NTYPE + n] : 0.f;
            } else if (i < 192512) {
                int t = i - 159744; int n = t >> 8, k = t & 255; v = wc1[(size_t)k * 128 + n];
            } else {
                int t = i - 192512; int n = t >> 8, k = t & 255; v = wl1[(size_t)k * 128 + n];
            }
            outw[i] = (_Float16)v;
        } else {
            int v = i - NW_TOT;                 // crystal id 0..4096
            int lo = 0, hi = N;
            while (lo < hi) { int mid = (lo + hi) >> 1; if (batch[mid] < v) lo = mid + 1; else hi = mid; }
            lb[v] = lo;
        }
    }
}

// One block = 16 crystals, 512 threads (8 waves). MFMA 16x16x32_f16.
// Deep unrolls keep many B-fragment loads in flight (R20: VGPR=28 -> no pipelining).
__global__ __launch_bounds__(THREADS, 2) void crystal_kernel(
    const float* __restrict__ t_emb,
    const _Float16* __restrict__ wpk, const int* __restrict__ lb,
    const float* __restrict__ b1a, const float* __restrict__ b2a,
    const float* __restrict__ bc1, const float* __restrict__ bl1,
    const float* __restrict__ wc2, const float* __restrict__ bc2,
    const float* __restrict__ wl2, const float* __restrict__ bl2,
    const float* __restrict__ bt,
    float* __restrict__ coord_b,     // ws [B,3]
    f32x4_n* __restrict__ logits_b4, // ws [B,25] f4
    float* __restrict__ cell_out)    // d_out+N*3 [B,6]
{
    const _Float16* wp1 = wpk;
    const _Float16* wp2 = wpk + 65536;
    const _Float16* wpt = wpk + 131072;
    const _Float16* wpc = wpk + 159744;
    const _Float16* wpl = wpk + 192512;

    __shared__ _Float16 bufA[RPB * ST];   // h0, then h
    __shared__ _Float16 bufB[RPB * ST];   // h1, then gc(0..127)/gl(128..255)
    __shared__ float logits_s[RPB * 104];
    __shared__ int   lb_s[RPB + 1];
    __shared__ float cnt_s[RPB];

    const int tid = threadIdx.x;
    const int R0  = blockIdx.x * RPB;

    if (tid <= RPB) lb_s[tid] = lb[R0 + tid];

    // stage t_emb rows R0..R0+15 -> f16 LDS (each thread 8 floats)
    {
        int r = tid >> 5, k0 = (tid & 31) * 8;
        float4 v0 = LD4(&t_emb[(size_t)(R0 + r) * HDIM + k0]);
        float4 v1 = LD4(&t_emb[(size_t)(R0 + r) * HDIM + k0 + 4]);
        f16x8 h = {(_Float16)v0.x, (_Float16)v0.y, (_Float16)v0.z, (_Float16)v0.w,
                   (_Float16)v1.x, (_Float16)v1.y, (_Float16)v1.z, (_Float16)v1.w};
        *(f16x8*)&bufA[r * ST + k0] = h;
    }
    __syncthreads();
    if (tid < RPB) cnt_s[tid] = (float)(lb_s[tid + 1] - lb_s[tid]);

    const int lane = tid & 63;
    const int wv   = tid >> 6;     // wave 0..7
    const int lm   = lane & 15;    // A row / B col
    const int lk   = lane >> 4;    // k sub-block (x8) / C row group (x4)

    // ---------------- layer 1: h1 = silu(h0 @ w1a + b1a)   bufA -> bufB
    {
        f32x4 a0 = {0.f,0.f,0.f,0.f}, a1 = {0.f,0.f,0.f,0.f};
        const int n0 = wv * 32 + lm, n1 = n0 + 16;
#pragma unroll
        for (int k0 = 0; k0 < 8; ++k0) {
            f16x8 af = *(const f16x8*)&bufA[lm * ST + k0 * 32 + lk * 8];
            f16x8 b0 = *(const f16x8*)&wp1[(size_t)n0 * 256 + k0 * 32 + lk * 8];
            f16x8 b1 = *(const f16x8*)&wp1[(size_t)n1 * 256 + k0 * 32 + lk * 8];
            a0 = MFMA(af, b0, a0);
            a1 = MFMA(af, b1, a1);
        }
        float bb0 = b1a[n0], bb1 = b1a[n1];
#pragma unroll
        for (int g = 0; g < 4; ++g) {
            int m = lk * 4 + g;
            bufB[m * ST + n0] = (_Float16)silu_f(a0[g] + bb0);
            bufB[m * ST + n1] = (_Float16)silu_f(a1[g] + bb1);
        }
    }
    __syncthreads();

    // ---------------- layer 2: h = h1 @ w2a + b2a          bufB -> bufA
    {
        f32x4 a0 = {0.f,0.f,0.f,0.f}, a1 = {0.f,0.f,0.f,0.f};
        const int n0 = wv * 32 + lm, n1 = n0 + 16;
#pragma unroll
        for (int k0 = 0; k0 < 8; ++k0) {
            f16x8 af = *(const f16x8*)&bufB[lm * ST + k0 * 32 + lk * 8];
            f16x8 b0 = *(const f16x8*)&wp2[(size_t)n0 * 256 + k0 * 32 + lk * 8];
            f16x8 b1 = *(const f16x8*)&wp2[(size_t)n1 * 256 + k0 * 32 + lk * 8];
            a0 = MFMA(af, b0, a0);
            a1 = MFMA(af, b1, a1);
        }
        float bb0 = b2a[n0], bb1 = b2a[n1];
#pragma unroll
        for (int g = 0; g < 4; ++g) {
            int m = lk * 4 + g;
            bufA[m * ST + n0] = (_Float16)(a0[g] + bb0);
            bufA[m * ST + n1] = (_Float16)(a1[g] + bb1);
        }
    }
    __syncthreads();

    // ------- merged: logits (waves 0-6) + coord head + cell head (all waves)
    {
        f32x4 aL = {0.f,0.f,0.f,0.f}, aC = aL, aG = aL;
        const bool hasL = (wv < 7);
        const int n = wv * 16 + lm;
#pragma unroll 4
        for (int k0 = 0; k0 < 8; ++k0) {
            f16x8 af = *(const f16x8*)&bufA[lm * ST + k0 * 32 + lk * 8];
            if (hasL) {
                f16x8 bL = *(const f16x8*)&wpt[(size_t)n * 256 + k0 * 32 + lk * 8];
                aL = MFMA(af, bL, aL);
            }
            f16x8 bC = *(const f16x8*)&wpc[(size_t)n * 256 + k0 * 32 + lk * 8];
            aC = MFMA(af, bC, aC);
            f16x8 bG = *(const f16x8*)&wpl[(size_t)n * 256 + k0 * 32 + lk * 8];
            aG = MFMA(af, bG, aG);
        }
        const bool wrL = hasL && (n < NTYPE);
        float btv = wrL ? bt[n] : 0.f;
        float bcv = bc1[n], blv = bl1[n];
#pragma unroll
        for (int g = 0; g < 4; ++g) {
            int m = lk * 4 + g;
            if (wrL) logits_s[m * 104 + n] = aL[g] + btv;
            bufB[m * ST + n]       = (_Float16)silu_f(aC[g] + bcv);
            bufB[m * ST + 128 + n] = (_Float16)silu_f(aG[g] * cnt_s[m] + blv);
        }
    }
    __syncthreads();

    // ---------------- logits table: 400 f4 writes, strided over 512 thr
    {
        const f32x4_n* ls4 = (const f32x4_n*)logits_s;
        for (int t2 = tid; t2 < 25 * RPB; t2 += THREADS) {
            int r = t2 / 25, q = t2 - 25 * r;
            logits_b4[(size_t)(R0 + r) * 25 + q] = ls4[r * 26 + q];
        }
    }

    // ---------------- tiny heads
    if (tid < RPB * 3) {                 // coord rows -> coord_b
        int r = tid / 3, c = tid - 3 * r;
        float a = 0.f;
#pragma unroll 8
        for (int k = 0; k < 128; ++k)
            a += (float)bufB[r * ST + k] * wc2[k * 3 + c];
        coord_b[(size_t)(R0 + r) * 3 + c] = a + bc2[c];
    } else if (tid >= 64 && tid < 64 + RPB * 6) {   // cell rows -> d_out
        int t2 = tid - 64;
        int r = t2 / 6, c = t2 - 6 * r;
        float a = 0.f;
#pragma unroll 8
        for (int k = 0; k < 128; ++k)
            a += (float)bufB[r * ST + 128 + k] * wl2[k * 6 + c];
        cell_out[(size_t)(R0 + r) * 6 + c] = a + bl2[c];
    }
}

// Gather per-crystal tables to per-atom outputs. 2048 blocks = full store-queue depth.
__global__ __launch_bounds__(256) void scatter_kernel(
    const int* __restrict__ batch,
    const float*  __restrict__ coord_b,
    const f32x4_n* __restrict__ logits_b4,  // [B][25] f4
    float*  __restrict__ out_coord,         // [N*3]
    f32x4_n* __restrict__ out_logits4,      // [N*25] f4
    int N)
{
    const int stride = gridDim.x * blockDim.x;
    const int g0 = blockIdx.x * blockDim.x + threadIdx.x;

    const int tot_c = N * 3;
    for (int g = g0; g < tot_c; g += stride) {
        unsigned ug = (unsigned)g;
        unsigned i = ug / 3u;
        unsigned c = ug - i * 3u;
        __builtin_nontemporal_store(coord_b[3u * (unsigned)batch[i] + c], &out_coord[g]);
    }

    const int tot_l = N * 25;
    for (int g = g0; g < tot_l; g += stride) {
        unsigned ug = (unsigned)g;
        unsigned i = ug / 25u;
        unsigned q = ug - i * 25u;
        f32x4_n v = logits_b4[25u * (unsigned)batch[i] + q];
        __builtin_nontemporal_store(v, &out_logits4[g]);
    }
}

extern "C" void kernel_launch(void* const* d_in, const int* in_sizes, int n_in,
                              void* d_out, int out_size, void* d_ws, size_t ws_size,
                              hipStream_t stream)
{
    const int*   batch = (const int*)d_in[1];
    const float* t_emb = (const float*)d_in[3];
    const float* w1a = (const float*)d_in[4];
    const float* b1a = (const float*)d_in[5];
    const float* w2a = (const float*)d_in[6];
    const float* b2a = (const float*)d_in[7];
    const float* wc1 = (const float*)d_in[8];
    const float* bc1 = (const float*)d_in[9];
    const float* wc2 = (const float*)d_in[10];
    const float* bc2 = (const float*)d_in[11];
    const float* wl1 = (const float*)d_in[12];
    const float* bl1 = (const float*)d_in[13];
    const float* wl2 = (const float*)d_in[14];
    const float* bl2 = (const float*)d_in[15];
    const float* wt  = (const float*)d_in[16];
    const float* bt  = (const float*)d_in[17];

    const int N = in_sizes[1];        // 500000
    const int B = in_sizes[2] / 9;    // 4096

    float* out        = (float*)d_out;
    float* out_coord  = out;                                   // [N,3]
    float* cell_out   = out + (size_t)N * 3;                   // [B,6]
    float* out_logits = out + (size_t)N * 3 + (size_t)B * 6;   // [N,100]

    _Float16* wpk   = (_Float16*)d_ws;                         // 225280 halves
    float* logits_b = (float*)(wpk + NW_TOT);                  // B*100 floats
    float* coord_b  = logits_b + (size_t)B * NTYPE;            // B*3 floats
    int*   lbw      = (int*)(coord_b + (size_t)B * 3);         // 4097 ints

    prep_kernel<<<896, 256, 0, stream>>>(w1a, w2a, wt, wc1, wl1, batch, N, wpk, lbw);

    crystal_kernel<<<B / RPB, THREADS, 0, stream>>>(
        t_emb, wpk, lbw,
        b1a, b2a, bc1, bl1,
        wc2, bc2, wl2, bl2, bt,
        coord_b, (f32x4_n*)logits_b, cell_out);

    scatter_kernel<<<2048, 256, 0, stream>>>(
        batch, coord_b, (const f32x4_n*)logits_b,
        out_coord, (f32x4_n*)out_logits, N);
}